// Round 8
// baseline (736.809 us; speedup 1.0000x reference)
//
#include <hip/hip_runtime.h>

// QuantizedLinear: out[m][n] = 0.01 * sum_k x[m][k]*(q[n][k]-8) + (0.01*0.047)*qbias[n]
// M=16384, N=4096, K=4096.
// R8: R6 structure (256x256, BK=64 zero-conflict swizzle, 16x16 MFMA,
// 1 barrier/K-tile, counted waits, flipped XCD swizzle) + FUSED x fp32->bf16:
// A is reg-staged (global fp32 loads -> cvt -> swizzled ds_write), cvt_x
// pre-pass eliminated. A ring 2 + B ring 2 = 128 KiB LDS. Last tile peeled.

typedef __bf16 bf16x8 __attribute__((ext_vector_type(8)));
typedef float f32x4 __attribute__((ext_vector_type(4)));
typedef unsigned short u16;
typedef u16 u16x8 __attribute__((ext_vector_type(8)));

static constexpr int Kdim = 4096;
static constexpr int Ndim = 4096;
static constexpr int BM = 256, BN = 256, BK = 64;
static constexpr int NKT = Kdim / BK;          // 64 K-tiles
static constexpr int TBUF = BM * BK;           // 16384 halfwords = 32 KiB per buffer

__device__ __forceinline__ u16 f2bf(float f) {
  union { float f; unsigned u; } c; c.f = f;
  unsigned u = c.u;
  return (u16)((u + 0x7FFFu + ((u >> 16) & 1u)) >> 16);  // RNE
}

// ---- pre-pass: packed nibbles -> bf16 integer weights (q-8), exact ----
__global__ __launch_bounds__(256) void dequant_w_kernel(const int* __restrict__ pw,
                                                        u16* __restrict__ wb, int n4) {
  int stride = gridDim.x * blockDim.x;
  for (int i = blockIdx.x * blockDim.x + threadIdx.x; i < n4; i += stride) {
    int4 v = reinterpret_cast<const int4*>(pw)[i];
    int a[4] = {v.x, v.y, v.z, v.w};
    u16x8 o;
#pragma unroll
    for (int j = 0; j < 4; ++j) {
      o[2 * j]     = f2bf((float)((a[j] & 15) - 8));
      o[2 * j + 1] = f2bf((float)(((a[j] >> 4) & 15) - 8));
    }
    reinterpret_cast<u16x8*>(wb)[i] = o;
  }
}

__device__ __forceinline__ void gload16(const u16* g, const u16* l) {
  __builtin_amdgcn_global_load_lds(
      (const __attribute__((address_space(1))) void*)g,
      (__attribute__((address_space(3))) void*)l,
      16, 0, 0);
}

__device__ __forceinline__ bf16x8 cvt8(float4 lo, float4 hi) {
  bf16x8 v;
  v[0] = (__bf16)lo.x; v[1] = (__bf16)lo.y; v[2] = (__bf16)lo.z; v[3] = (__bf16)lo.w;
  v[4] = (__bf16)hi.x; v[5] = (__bf16)hi.y; v[6] = (__bf16)hi.z; v[7] = (__bf16)hi.w;
  return v;
}

// ---- main GEMM (A = fp32 x, converted in-kernel) ----
__global__ __launch_bounds__(512, 2) void gemm_kernel(const float* __restrict__ A32,
                                                      const u16* __restrict__ B,
                                                      const int* __restrict__ qbias,
                                                      float* __restrict__ C,
                                                      int Ntiles) {
  extern __shared__ u16 smem[];
  u16* As = smem;                    // 2 x 256x64 = 64 KiB (ring of 2, reg-staged)
  u16* Bs = smem + 2 * TBUF;         // 2 x 256x64 = 64 KiB (ring of 2, gload_lds)

  const int tid = threadIdx.x;
  const int lane = tid & 63;
  const int wave = tid >> 6;
  const int wm = wave >> 2, wn = wave & 3;   // 2 (M) x 4 (N) waves, each 128x64

  // T1 (flipped): bx fast within XCD chunk -> A panel L2-resident per XCD.
  const int cpx = gridDim.x >> 3;
  const int bid = blockIdx.x;
  const int swz = (bid & 7) * cpx + (bid >> 3);
  const int bx = swz % Ntiles;
  const int by = swz / Ntiles;
  const int m0 = by * BM, n0 = bx * BN;

  // ---- staging geometry (source carries inverse of the read swizzle) ----
  const int srow = tid >> 3;
  const int fcol = (((tid & 7) ^ (srow & 7)) << 3);  // element col offset
  const u16* pb[4];
  const float* pa32[4];
#pragma unroll
  for (int i = 0; i < 4; ++i) {
    pb[i]   = B   + (size_t)(n0 + i * 64 + srow) * Kdim + fcol;
    pa32[i] = A32 + (size_t)(m0 + i * 64 + srow) * Kdim + fcol;
  }
  const int wbase = (tid & 0x1C0) * 8;   // wave-uniform base for gload_lds
  const int dstA = tid * 8;              // halfword dest for ds_write (== wbase+lane*8)

  // ---- ds_read geometry: phys slot = s_log ^ (row&7); row&7 == lane&7 ----
  const int e0 = ((lane >> 4) ^ (lane & 7)) << 3;    // k-half 0 slot offset (halfwords)
  const int e1 = e0 ^ 32;                            // k-half 1
  const int arow = (wm * 128 + (lane & 15)) * 64;    // A halfword row base
  const int brow = (wn * 64 + (lane & 15)) * 64;     // B halfword row base

  f32x4 acc[8][4] = {};
  float4 st[8];

  // ---- prologue: load+convert A(0), gload B(0) ----
#pragma unroll
  for (int i = 0; i < 4; ++i) {
    st[2 * i]     = *(const float4*)(pa32[i]);
    st[2 * i + 1] = *(const float4*)(pa32[i] + 4);
  }
#pragma unroll
  for (int i = 0; i < 4; ++i) gload16(pb[i], Bs + i * 4096 + wbase);
  asm volatile("s_waitcnt vmcnt(4)" ::: "memory");   // 8 A-loads done
#pragma unroll
  for (int i = 0; i < 4; ++i)
    *(bf16x8*)(As + i * 4096 + dstA) = cvt8(st[2 * i], st[2 * i + 1]);
  asm volatile("s_waitcnt vmcnt(0) lgkmcnt(0)" ::: "memory");
  __builtin_amdgcn_s_barrier();

#define MFMAS(ACC_BASE, AF, KH)                                               \
    __builtin_amdgcn_sched_barrier(0);                                        \
    __builtin_amdgcn_s_setprio(1);                                            \
    _Pragma("unroll")                                                         \
    for (int m = 0; m < 4; ++m)                                               \
      _Pragma("unroll")                                                       \
      for (int n = 0; n < 4; ++n)                                             \
        acc[(ACC_BASE) + m][n] = __builtin_amdgcn_mfma_f32_16x16x32_bf16(     \
            AF[m], bf[n][KH], acc[(ACC_BASE) + m][n], 0, 0, 0);               \
    __builtin_amdgcn_s_setprio(0);

  for (int t = 0; t < NKT - 1; ++t) {
    const u16* aL = As + (t & 1) * TBUF;
    const u16* bL = Bs + (t & 1) * TBUF;
    u16* aW = As + ((t + 1) & 1) * TBUF;
    const u16* bW = Bs + ((t + 1) & 1) * TBUF;
    const int ko = (t + 1) * BK;   // element offset for both A (fp32) and B (bf16)

    bf16x8 a0[4], a1[4], bf[4][2];

    // ---- tile-start reads (12) ----
#pragma unroll
    for (int m = 0; m < 4; ++m)
      a0[m] = *(const bf16x8*)(aL + arow + m * 1024 + e0);
#pragma unroll
    for (int n = 0; n < 4; ++n)
      bf[n][0] = *(const bf16x8*)(bL + brow + n * 1024 + e0);
#pragma unroll
    for (int n = 0; n < 4; ++n)
      bf[n][1] = *(const bf16x8*)(bL + brow + n * 1024 + e1);

    // ---- P0: read a1(kh0); issue A-loads i=0,1; gload B0,B1; MFMA kh0 lo ----
#pragma unroll
    for (int m = 0; m < 4; ++m)
      a1[m] = *(const bf16x8*)(aL + arow + 4096 + m * 1024 + e0);
    st[0] = *(const float4*)(pa32[0] + ko);
    st[1] = *(const float4*)(pa32[0] + ko + 4);
    st[2] = *(const float4*)(pa32[1] + ko);
    st[3] = *(const float4*)(pa32[1] + ko + 4);
    gload16(pb[0] + ko, bW + 0 * 4096 + wbase);
    gload16(pb[1] + ko, bW + 1 * 4096 + wbase);
    asm volatile("s_waitcnt lgkmcnt(4)" ::: "memory");
    MFMAS(0, a0, 0)

    // ---- P1: read a0(kh1); issue A-loads i=2,3; gload B2,B3; MFMA kh0 hi ----
#pragma unroll
    for (int m = 0; m < 4; ++m)
      a0[m] = *(const bf16x8*)(aL + arow + m * 1024 + e1);
    st[4] = *(const float4*)(pa32[2] + ko);
    st[5] = *(const float4*)(pa32[2] + ko + 4);
    st[6] = *(const float4*)(pa32[3] + ko);
    st[7] = *(const float4*)(pa32[3] + ko + 4);
    gload16(pb[2] + ko, bW + 2 * 4096 + wbase);
    gload16(pb[3] + ko, bW + 3 * 4096 + wbase);
    asm volatile("s_waitcnt lgkmcnt(4)" ::: "memory");
    MFMAS(4, a1, 0)

    // ---- P2: read a1(kh1); cvt+write A(t+1) half 1; MFMA kh1 lo ----
#pragma unroll
    for (int m = 0; m < 4; ++m)
      a1[m] = *(const bf16x8*)(aL + arow + 4096 + m * 1024 + e1);
    asm volatile("s_waitcnt vmcnt(8)" ::: "memory");   // st[0..3] landed
    *(bf16x8*)(aW + 0 * 4096 + dstA) = cvt8(st[0], st[1]);
    *(bf16x8*)(aW + 1 * 4096 + dstA) = cvt8(st[2], st[3]);
    asm volatile("s_waitcnt lgkmcnt(6)" ::: "memory");
    MFMAS(0, a0, 1)

    // ---- P3: cvt+write A(t+1) half 2; MFMA kh1 hi; boundary ----
    asm volatile("s_waitcnt vmcnt(2)" ::: "memory");   // st[4..7] landed
    *(bf16x8*)(aW + 2 * 4096 + dstA) = cvt8(st[4], st[5]);
    *(bf16x8*)(aW + 3 * 4096 + dstA) = cvt8(st[6], st[7]);
    asm volatile("s_waitcnt lgkmcnt(4)" ::: "memory");
    MFMAS(4, a1, 1)
    __builtin_amdgcn_sched_barrier(0);
    asm volatile("s_waitcnt vmcnt(0) lgkmcnt(0)" ::: "memory");  // B(t+1) + writes done
    __builtin_amdgcn_s_barrier();
  }

  // ---- peeled last tile (no staging; tight lgkm counts) ----
  {
    const int t = NKT - 1;
    const u16* aL = As + (t & 1) * TBUF;
    const u16* bL = Bs + (t & 1) * TBUF;
    bf16x8 a0[4], a1[4], bf[4][2];
#pragma unroll
    for (int m = 0; m < 4; ++m)
      a0[m] = *(const bf16x8*)(aL + arow + m * 1024 + e0);
#pragma unroll
    for (int n = 0; n < 4; ++n)
      bf[n][0] = *(const bf16x8*)(bL + brow + n * 1024 + e0);
#pragma unroll
    for (int n = 0; n < 4; ++n)
      bf[n][1] = *(const bf16x8*)(bL + brow + n * 1024 + e1);
#pragma unroll
    for (int m = 0; m < 4; ++m)
      a1[m] = *(const bf16x8*)(aL + arow + 4096 + m * 1024 + e0);
    asm volatile("s_waitcnt lgkmcnt(4)" ::: "memory");
    MFMAS(0, a0, 0)
#pragma unroll
    for (int m = 0; m < 4; ++m)
      a0[m] = *(const bf16x8*)(aL + arow + m * 1024 + e1);
    asm volatile("s_waitcnt lgkmcnt(4)" ::: "memory");
    MFMAS(4, a1, 0)
#pragma unroll
    for (int m = 0; m < 4; ++m)
      a1[m] = *(const bf16x8*)(aL + arow + 4096 + m * 1024 + e1);
    asm volatile("s_waitcnt lgkmcnt(4)" ::: "memory");
    MFMAS(0, a0, 1)
    asm volatile("s_waitcnt lgkmcnt(0)" ::: "memory");
    MFMAS(4, a1, 1)
  }
#undef MFMAS

  // epilogue: C/D layout col=lane&15, row=(lane>>4)*4+j
  const float wscale = 0.01f;
  const float bscale = (float)(0.01 * 0.047);
  const int col0 = n0 + wn * 64 + (lane & 15);
  const int row0 = m0 + wm * 128 + ((lane >> 4) << 2);
#pragma unroll
  for (int n = 0; n < 4; ++n) {
    const int col = col0 + n * 16;
    const float bias = bscale * (float)qbias[col];
#pragma unroll
    for (int m = 0; m < 8; ++m) {
      const int rr = row0 + m * 16;
#pragma unroll
      for (int j = 0; j < 4; ++j)
        C[(size_t)(rr + j) * Ndim + col] = wscale * acc[m][n][j] + bias;
    }
  }
}

extern "C" void kernel_launch(void* const* d_in, const int* in_sizes, int n_in,
                              void* d_out, int out_size, void* d_ws, size_t ws_size,
                              hipStream_t stream) {
  const float* x  = (const float*)d_in[0];
  const int*   pw = (const int*)d_in[1];
  const int*   qb = (const int*)d_in[2];
  float* out = (float*)d_out;

  const int M = in_sizes[0] / Kdim;  // 16384

  u16* wb = (u16*)d_ws;              // N*K bf16 weights (33.5 MB)

  dequant_w_kernel<<<1024, 256, 0, stream>>>(pw, wb, Ndim * Kdim / 8);

  const int Ntiles = Ndim / BN;                  // 16
  const int nwg = (M / BM) * Ntiles;             // 1024, multiple of 8
  static const size_t lds_bytes = 4u * TBUF * sizeof(u16);  // 128 KiB
  (void)hipFuncSetAttribute((const void*)gemm_kernel,
                            hipFuncAttributeMaxDynamicSharedMemorySize,
                            (int)lds_bytes);
  gemm_kernel<<<nwg, 512, lds_bytes, stream>>>(x, wb, qb, out, Ntiles);
}

// Round 11
// 549.922 us; speedup vs baseline: 1.3398x; 1.3398x over previous
//
#include <hip/hip_runtime.h>

// QuantizedLinear: out[m][n] = 0.01 * sum_k x[m][k]*(q[n][k]-8) + (0.01*0.047)*qbias[n]
// M=16384, N=4096, K=4096.
// R11 = R10 with the A-staging grouping fixed (race repair):
// A mh0 reads rows {0-63, 128-191} (per-wave wm*128+0..63), so staging groups are
// g0={pa[0],pa[2]} (mh0 rows), g1={pa[1],pa[3]} (mh1 rows) — NOT contiguous halves.
// 8-phase m201-style schedule, 256x256, BK=64, full A+B 2-tile double buffer,
// counted vmcnt(6/8/4) at ph3/5/7 only, zero-conflict both-sides XOR swizzle,
// flipped XCD swizzle, setprio. bf16 (absmax 0.0625).

typedef __bf16 bf16x8 __attribute__((ext_vector_type(8)));
typedef float f32x4 __attribute__((ext_vector_type(4)));
typedef unsigned short u16;
typedef u16 u16x4 __attribute__((ext_vector_type(4)));
typedef u16 u16x8 __attribute__((ext_vector_type(8)));

static constexpr int Kdim = 4096;
static constexpr int Ndim = 4096;
static constexpr int BM = 256, BN = 256, BK = 64;
static constexpr int NKT = Kdim / BK;          // 64 K-tiles
static constexpr int TBUF = BM * BK;           // 16384 halfwords = 32 KiB per buffer

__device__ __forceinline__ u16 f2bf(float f) {
  union { float f; unsigned u; } c; c.f = f;
  unsigned u = c.u;
  return (u16)((u + 0x7FFFu + ((u >> 16) & 1u)) >> 16);  // RNE
}

// ---- pre-pass 1: x fp32 -> bf16 ----
__global__ __launch_bounds__(256) void cvt_x_kernel(const float* __restrict__ x,
                                                    u16* __restrict__ xb, int n4) {
  int stride = gridDim.x * blockDim.x;
  for (int i = blockIdx.x * blockDim.x + threadIdx.x; i < n4; i += stride) {
    float4 v = reinterpret_cast<const float4*>(x)[i];
    u16x4 o;
    o.x = f2bf(v.x); o.y = f2bf(v.y); o.z = f2bf(v.z); o.w = f2bf(v.w);
    reinterpret_cast<u16x4*>(xb)[i] = o;
  }
}

// ---- pre-pass 2: packed nibbles -> bf16 integer weights (q-8), exact ----
__global__ __launch_bounds__(256) void dequant_w_kernel(const int* __restrict__ pw,
                                                        u16* __restrict__ wb, int n4) {
  int stride = gridDim.x * blockDim.x;
  for (int i = blockIdx.x * blockDim.x + threadIdx.x; i < n4; i += stride) {
    int4 v = reinterpret_cast<const int4*>(pw)[i];
    int a[4] = {v.x, v.y, v.z, v.w};
    u16x8 o;
#pragma unroll
    for (int j = 0; j < 4; ++j) {
      o[2 * j]     = f2bf((float)((a[j] & 15) - 8));
      o[2 * j + 1] = f2bf((float)(((a[j] >> 4) & 15) - 8));
    }
    reinterpret_cast<u16x8*>(wb)[i] = o;
  }
}

__device__ __forceinline__ void gload16(const u16* g, const u16* l) {
  __builtin_amdgcn_global_load_lds(
      (const __attribute__((address_space(1))) void*)g,
      (__attribute__((address_space(3))) void*)l,
      16, 0, 0);
}

// ---- main GEMM ----
__global__ __launch_bounds__(512, 2) void gemm_kernel(const u16* __restrict__ A,
                                                      const u16* __restrict__ B,
                                                      const int* __restrict__ qbias,
                                                      float* __restrict__ C,
                                                      int Ntiles) {
  extern __shared__ u16 smem[];
  u16* As = smem;                    // 2 x 256x64 = 64 KiB (even/odd K-tile)
  u16* Bs = smem + 2 * TBUF;         // 2 x 256x64 = 64 KiB

  const int tid = threadIdx.x;
  const int lane = tid & 63;
  const int wave = tid >> 6;
  const int wm = wave >> 2, wn = wave & 3;   // 2 (M) x 4 (N) waves, each 128x64

  // Flipped XCD swizzle: bx fast within XCD chunk -> A panel L2-resident per XCD.
  const int cpx = gridDim.x >> 3;
  const int bid = blockIdx.x;
  const int swz = (bid & 7) * cpx + (bid >> 3);
  const int bx = swz % Ntiles;
  const int by = swz / Ntiles;
  const int m0 = by * BM, n0 = bx * BN;

  // ---- staging geometry (source carries inverse of the read swizzle) ----
  const int srow = tid >> 3;
  const int fcol = (((tid & 7) ^ (srow & 7)) << 3);  // halfword col offset
  const u16* pa[4];
  const u16* pb[4];
#pragma unroll
  for (int i = 0; i < 4; ++i) {
    pa[i] = A + (size_t)(m0 + i * 64 + srow) * Kdim + fcol;
    pb[i] = B + (size_t)(n0 + i * 64 + srow) * Kdim + fcol;
  }
  const int wbase = (tid & 0x1C0) * 8;   // wave-uniform LDS halfword base (HW adds lane*16B)

  // ---- ds_read geometry: phys slot = s_log ^ (row&7); row&7 == lane&7 ----
  const int e0 = ((lane >> 4) ^ (lane & 7)) << 3;    // k-half 0 slot offset (halfwords)
  const int e1 = e0 ^ 32;                            // k-half 1
  const int arow = (wm * 128 + (lane & 15)) * 64;    // A halfword row base
  const int brow = (wn * 64 + (lane & 15)) * 64;     // B halfword row base

  f32x4 acc[8][4] = {};
  bf16x8 af[4], bq[2][4];

  // ---- prologue: tile0 full (8); then A(1)g0 = {pa[0],pa[2]} (mh0 rows),
  //      B(1)h0 = {pb[0],pb[1]} ----
#pragma unroll
  for (int i = 0; i < 4; ++i) gload16(pb[i], Bs + i * 4096 + wbase);
#pragma unroll
  for (int i = 0; i < 4; ++i) gload16(pa[i], As + i * 4096 + wbase);
  gload16(pa[0] + BK, As + TBUF + 0 * 4096 + wbase);
  gload16(pa[2] + BK, As + TBUF + 2 * 4096 + wbase);
  gload16(pb[0] + BK, Bs + TBUF + 0 * 4096 + wbase);
  gload16(pb[1] + BK, Bs + TBUF + 1 * 4096 + wbase);
  asm volatile("s_waitcnt vmcnt(4)" ::: "memory");   // tile0 landed; 4 prefetch in flight
  __builtin_amdgcn_s_barrier();

#define RD_A(BUF, MH, E)                                                      \
    _Pragma("unroll")                                                         \
    for (int m = 0; m < 4; ++m)                                               \
      af[m] = *(const bf16x8*)((BUF) + arow + (MH) * 4096 + m * 1024 + (E));
#define RD_B(KH, BUF, E)                                                      \
    _Pragma("unroll")                                                         \
    for (int n = 0; n < 4; ++n)                                               \
      bq[KH][n] = *(const bf16x8*)((BUF) + brow + n * 1024 + (E));
#define MF(BASE, KH)                                                          \
    __builtin_amdgcn_s_barrier();                                             \
    asm volatile("s_waitcnt lgkmcnt(0)" ::: "memory");                        \
    __builtin_amdgcn_sched_barrier(0);                                        \
    __builtin_amdgcn_s_setprio(1);                                            \
    _Pragma("unroll")                                                         \
    for (int m = 0; m < 4; ++m)                                               \
      _Pragma("unroll")                                                       \
      for (int n = 0; n < 4; ++n)                                             \
        acc[(BASE) + m][n] = __builtin_amdgcn_mfma_f32_16x16x32_bf16(         \
            af[m], bq[KH][n], acc[(BASE) + m][n], 0, 0, 0);                   \
    __builtin_amdgcn_s_setprio(0);

  for (int j = 0; j < NKT / 2; ++j) {
    const int t = 2 * j;
    const bool s2 = (t + 2) < NKT;
    const bool s3 = (t + 3) < NKT;
    const int k1 = (t + 1) * BK, k2 = (t + 2) * BK, k3 = (t + 3) * BK;
    const u16* aL0 = As;            const u16* bL0 = Bs;
    const u16* aL1 = As + TBUF;     const u16* bL1 = Bs + TBUF;

    // ===== ph0: (t, mh0, kh0); stage B(t+1)h1, A(t+1)g1={pa[1],pa[3]} -> buf1 =====
    RD_A(aL0, 0, e0)
    RD_B(0, bL0, e0)
    gload16(pb[2] + k1, Bs + TBUF + 2 * 4096 + wbase);
    gload16(pb[3] + k1, Bs + TBUF + 3 * 4096 + wbase);
    gload16(pa[1] + k1, As + TBUF + 1 * 4096 + wbase);
    gload16(pa[3] + k1, As + TBUF + 3 * 4096 + wbase);
    MF(0, 0)
    __builtin_amdgcn_s_barrier();

    // ===== ph1: (t, mh0, kh1) =====
    RD_A(aL0, 0, e1)
    RD_B(1, bL0, e1)
    MF(0, 1)
    __builtin_amdgcn_s_barrier();

    // ===== ph2: (t, mh1, kh0); stage B(t+2)h0 -> buf0 =====
    RD_A(aL0, 1, e0)
    if (s2) { gload16(pb[0] + k2, Bs + 0 * 4096 + wbase);
              gload16(pb[1] + k2, Bs + 1 * 4096 + wbase); }
    MF(4, 0)
    __builtin_amdgcn_s_barrier();

    // ===== ph3: (t, mh1, kh1); stage B(t+2)h1; vmcnt(6) =====
    // retires: A(t+1)g0 (prev ph6), B(t+1)h0 (prev ph7), B(t+1)h1 (ph0)
    RD_A(aL0, 1, e1)
    if (s2) { gload16(pb[2] + k2, Bs + 2 * 4096 + wbase);
              gload16(pb[3] + k2, Bs + 3 * 4096 + wbase); }
    MF(4, 1)
    if (s2) { asm volatile("s_waitcnt vmcnt(6)" ::: "memory"); }
    else    { asm volatile("s_waitcnt vmcnt(2)" ::: "memory"); }
    __builtin_amdgcn_s_barrier();

    // ===== ph4: (t+1, mh0, kh0) [reads A g0 rows + B all rows: all retired];
    //        stage A(t+2) full -> buf0 =====
    RD_A(aL1, 0, e0)
    RD_B(0, bL1, e0)
    if (s2) { gload16(pa[0] + k2, As + 0 * 4096 + wbase);
              gload16(pa[1] + k2, As + 1 * 4096 + wbase);
              gload16(pa[2] + k2, As + 2 * 4096 + wbase);
              gload16(pa[3] + k2, As + 3 * 4096 + wbase); }
    MF(0, 0)
    __builtin_amdgcn_s_barrier();

    // ===== ph5: (t+1, mh0, kh1); vmcnt(8) retires A(t+1)g1 =====
    RD_A(aL1, 0, e1)
    RD_B(1, bL1, e1)
    MF(0, 1)
    if (s2) { asm volatile("s_waitcnt vmcnt(8)" ::: "memory"); }
    else    { asm volatile("s_waitcnt vmcnt(0)" ::: "memory"); }
    __builtin_amdgcn_s_barrier();

    // ===== ph6: (t+1, mh1, kh0) [A g1 rows retired]; stage A(t+3)g0 -> buf1 =====
    RD_A(aL1, 1, e0)
    if (s3) { gload16(pa[0] + k3, As + TBUF + 0 * 4096 + wbase);
              gload16(pa[2] + k3, As + TBUF + 2 * 4096 + wbase); }
    MF(4, 0)
    __builtin_amdgcn_s_barrier();

    // ===== ph7: (t+1, mh1, kh1); stage B(t+3)h0 -> buf1; vmcnt(4) =====
    // retires B(t+2) full + A(t+2) full; leaves {A(t+3)g0, B(t+3)h0}
    RD_A(aL1, 1, e1)
    if (s3) { gload16(pb[0] + k3, Bs + TBUF + 0 * 4096 + wbase);
              gload16(pb[1] + k3, Bs + TBUF + 1 * 4096 + wbase); }
    MF(4, 1)
    if (s3) { asm volatile("s_waitcnt vmcnt(4)" ::: "memory"); }
    __builtin_amdgcn_s_barrier();
  }
#undef RD_A
#undef RD_B
#undef MF

  // epilogue: C/D layout col=lane&15, row=(lane>>4)*4+j
  const float wscale = 0.01f;
  const float bscale = (float)(0.01 * 0.047);
  const int col0 = n0 + wn * 64 + (lane & 15);
  const int row0 = m0 + wm * 128 + ((lane >> 4) << 2);
#pragma unroll
  for (int n = 0; n < 4; ++n) {
    const int col = col0 + n * 16;
    const float bias = bscale * (float)qbias[col];
#pragma unroll
    for (int m = 0; m < 8; ++m) {
      const int rr = row0 + m * 16;
#pragma unroll
      for (int j = 0; j < 4; ++j)
        C[(size_t)(rr + j) * Ndim + col] = wscale * acc[m][n][j] + bias;
    }
  }
}

extern "C" void kernel_launch(void* const* d_in, const int* in_sizes, int n_in,
                              void* d_out, int out_size, void* d_ws, size_t ws_size,
                              hipStream_t stream) {
  const float* x  = (const float*)d_in[0];
  const int*   pw = (const int*)d_in[1];
  const int*   qb = (const int*)d_in[2];
  float* out = (float*)d_out;

  const int M = in_sizes[0] / Kdim;  // 16384

  u16* xb = (u16*)d_ws;                                  // M*K bf16
  u16* wb = (u16*)((char*)d_ws + (size_t)M * Kdim * 2);  // N*K bf16

  cvt_x_kernel<<<2048, 256, 0, stream>>>(x, xb, M * Kdim / 4);
  dequant_w_kernel<<<1024, 256, 0, stream>>>(pw, wb, Ndim * Kdim / 8);

  const int Ntiles = Ndim / BN;                  // 16
  const int nwg = (M / BM) * Ntiles;             // 1024, multiple of 8
  static const size_t lds_bytes = 4u * TBUF * sizeof(u16);  // 128 KiB
  (void)hipFuncSetAttribute((const void*)gemm_kernel,
                            hipFuncAttributeMaxDynamicSharedMemorySize,
                            (int)lds_bytes);
  gemm_kernel<<<nwg, 512, lds_bytes, stream>>>(xb, wb, qb, out, Ntiles);
}